// Round 10
// baseline (615.467 us; speedup 1.0000x reference)
//
#include <hip/hip_runtime.h>

typedef unsigned int uint32;
typedef unsigned short ushort16;

typedef __attribute__((ext_vector_type(8))) short short8;
typedef __attribute__((ext_vector_type(4))) float f32x4;

#define BMAX 512   // max buckets (N <= 130816)

// ---------------------------------------------------------------------------
// GNN: h1 = relu((x + mean_agg(x)) @ W1 + b1)
//      h2 = relu((h1 + mean_agg(h1)) @ W2 + b2)
//      out = h2 @ Wp + bp
// R10: channel-sliced feature layout — 8 slices x 16ch, slice array 3.2MB
//      fits one XCD's 4MB L2; agg block's slice = blockIdx&7 (CP round-
//      robins blocks over XCDs) so gathers become XCD-local L2 hits.
//      gemm MFMA frag load/store rewired to sliced layout. Build unchanged.
// ---------------------------------------------------------------------------

__device__ __forceinline__ ushort16 f2bf(float f) {
    uint32 u = __float_as_uint(f);
    u += 0x7fffu + ((u >> 16) & 1u);       // round-to-nearest-even
    return (ushort16)(u >> 16);
}
__device__ __forceinline__ float bfhi(uint32 u) { return __uint_as_float(u & 0xffff0000u); }
__device__ __forceinline__ float bflo(uint32 u) { return __uint_as_float(u << 16); }
__device__ __forceinline__ uint32 pack2(float a, float b) {
    return (uint32)f2bf(a) | ((uint32)f2bf(b) << 16);
}

union U16 { uint4 u; short8 s; };
__device__ __forceinline__ short8 ld_frag(const ushort16* p) {
    U16 x; x.u = *(const uint4*)p; return x.s;
}

// exclusive scan of total[0..B) into bs[0..511] using 256 threads.
__device__ __forceinline__ void bucket_scan(const int* __restrict__ total, int B,
                                            int* bs /*[512]*/, int* sd /*[256]*/) {
    int tid = threadIdx.x;
    int v0 = (2 * tid     < B) ? total[2 * tid]     : 0;
    int v1 = (2 * tid + 1 < B) ? total[2 * tid + 1] : 0;
    int s = v0 + v1;
    sd[tid] = s;
    __syncthreads();
    for (int o = 1; o < 256; o <<= 1) {
        int t = (tid >= o) ? sd[tid - o] : 0;
        __syncthreads();
        sd[tid] += t;
        __syncthreads();
    }
    int excl = sd[tid] - s;
    bs[2 * tid]     = excl;
    bs[2 * tid + 1] = excl + v0;
    __syncthreads();
}

// A: per-chunk bucket histogram + x->bf16 SLICED cvt; blocks >= G1 do Wt prep.
__global__ __launch_bounds__(256)
void hist_cvt_prep_kernel(const int* __restrict__ tgt, int* __restrict__ hist,
                          const float* __restrict__ x, uint4* __restrict__ xbu4,
                          const float* __restrict__ W1, const float* __restrict__ W2,
                          ushort16* __restrict__ Wt1, ushort16* __restrict__ Wt2,
                          int E, int C, int B, int G1, int n64, int N) {
    int tid = threadIdx.x, blk = blockIdx.x;
    if (blk >= G1) {   // Wt prep blocks
        const float* W = (blk - G1) ? W2 : W1;
        ushort16* Wt = (blk - G1) ? Wt2 : Wt1;
        for (int i = tid; i < 16384; i += 256) {
            int k = i >> 7, c = i & 127;
            Wt[c * 128 + k] = f2bf(W[i]);
        }
        return;
    }
    __shared__ int lh[BMAX];
    for (int b = tid; b < B; b += 256) lh[b] = 0;
    __syncthreads();
    int e0 = blk * C, e1 = min(e0 + C, E);
    for (int e = e0 + tid; e < e1; e += 256)
        atomicAdd(&lh[tgt[e] >> 8], 1);
    // cvt: grid-stride over 64-float groups; write SLICED (slice=ch>>4)
    for (int i = blk * 256 + tid; i < n64; i += G1 * 256) {
        int n = i >> 1, h = i & 1;
        const float4* p = (const float4*)x + (size_t)n * 32 + h * 16;
#pragma unroll
        for (int j = 0; j < 4; ++j) {   // slice 4h+j holds channels 64h+16j..+15
            float4 a = p[4 * j], b = p[4 * j + 1], c = p[4 * j + 2], d = p[4 * j + 3];
            uint4 o0, o1;
            o0.x = pack2(a.x, a.y); o0.y = pack2(a.z, a.w);
            o0.z = pack2(b.x, b.y); o0.w = pack2(b.z, b.w);
            o1.x = pack2(c.x, c.y); o1.y = pack2(c.z, c.w);
            o1.z = pack2(d.x, d.y); o1.w = pack2(d.z, d.w);
            uint4* q = xbu4 + (size_t)(4 * h + j) * N * 2 + (size_t)n * 2;
            q[0] = o0; q[1] = o1;
        }
    }
    __syncthreads();
    for (int b = tid; b < B; b += 256) hist[blk * B + b] = lh[b];
}

// B: for each bucket b, exclusive scan of hist[g][b] over g; total[b] = sum
__global__ __launch_bounds__(256)
void colscan_kernel(int* __restrict__ hist, int* __restrict__ total, int G1, int B) {
    __shared__ int sd[256];
    __shared__ int carrySh;
    int b = blockIdx.x, tid = threadIdx.x;
    if (tid == 0) carrySh = 0;
    __syncthreads();
    for (int g0 = 0; g0 < G1; g0 += 256) {
        int g = g0 + tid;
        int v = (g < G1) ? hist[g * B + b] : 0;
        int c0 = carrySh;
        sd[tid] = v;
        __syncthreads();
        for (int o = 1; o < 256; o <<= 1) {
            int t = (tid >= o) ? sd[tid - o] : 0;
            __syncthreads();
            sd[tid] += t;
            __syncthreads();
        }
        if (g < G1) hist[g * B + b] = sd[tid] - v + c0;
        int tot = sd[255];
        __syncthreads();
        if (tid == 0) carrySh = c0 + tot;
        __syncthreads();
    }
    if (tid == 0) total[b] = carrySh;
}

// D: scatter edges into bucket order; packed uint32 = (t&255)<<24 | src.
__global__ __launch_bounds__(256)
void partition_kernel(const int* __restrict__ src, const int* __restrict__ tgt,
                      const int* __restrict__ hist, const int* __restrict__ total,
                      uint32* __restrict__ ebuf, int E, int C, int B) {
    __shared__ int bs[512];
    __shared__ int sd[256];
    __shared__ int cur[BMAX];
    int tid = threadIdx.x, blk = blockIdx.x;
    bucket_scan(total, B, bs, sd);
    for (int b = tid; b < B; b += 256) cur[b] = hist[blk * B + b] + bs[b];
    __syncthreads();
    int e0 = blk * C, e1 = min(e0 + C, E);
    for (int e = e0 + tid; e < e1; e += 256) {
        int t = tgt[e], s = src[e];
        int slot = atomicAdd(&cur[t >> 8], 1);
        ebuf[slot] = ((uint32)(t & 255) << 24) | (uint32)s;
    }
}

// E: per-bucket local count + scan -> offsets; LDS-cursor scatter -> csr.
__global__ __launch_bounds__(256)
void csr_kernel(const uint32* __restrict__ ebuf, const int* __restrict__ total,
                int* __restrict__ offsets, int* __restrict__ csr, int N, int B, int E) {
    __shared__ int bs[512];
    __shared__ int sd[256];
    __shared__ int cnt[256];
    int b = blockIdx.x, tid = threadIdx.x;
    bucket_scan(total, B, bs, sd);
    int s = bs[b];
    int n = bs[b + 1] - s;
    int t0 = b << 8;
    cnt[tid] = 0;
    __syncthreads();
    for (int i = tid; i < n; i += 256) atomicAdd(&cnt[ebuf[s + i] >> 24], 1);
    __syncthreads();
    int v = cnt[tid];
    sd[tid] = v;
    __syncthreads();
    for (int o = 1; o < 256; o <<= 1) {
        int t = (tid >= o) ? sd[tid - o] : 0;
        __syncthreads();
        sd[tid] += t;
        __syncthreads();
    }
    int excl = sd[tid] - v;
    int t = t0 + tid;
    if (t < N) offsets[t] = s + excl;
    if (b == B - 1 && tid == 255) offsets[N] = E;
    __syncthreads();
    cnt[tid] = s + excl;   // cursor
    __syncthreads();
    for (int i = tid; i < n; i += 256) {
        uint32 e = ebuf[s + i];
        int slot = atomicAdd(&cnt[e >> 24], 1);
        csr[slot] = (int)(e & 0x00FFFFFFu);
    }
}

// Sliced agg: block's slice = blockIdx&7 (XCD-local 3.2MB slice in L2).
// 8 waves/block, 1 node/wave; wave = 8 edge-groups x 8 lanes x uint32 (2 ch);
// 16 edges in flight. xor-reduce over groups; group 0 writes 32B.
__global__ __launch_bounds__(512)
void agg_sliced_kernel(const ushort16* __restrict__ xin,
                       const int* __restrict__ offsets, const int* __restrict__ csr,
                       ushort16* __restrict__ xout, int N) {
    int bk = blockIdx.x;
    int s = bk & 7;
    int wave = threadIdx.x >> 6;
    int node = (bk >> 3) * 8 + wave;
    if (node >= N) return;
    int lane = threadIdx.x & 63;
    int g = lane >> 3, li = lane & 7;
    const uint32* bin = (const uint32*)(xin + (size_t)s * N * 16);
    int s0 = offsets[node];
    int deg = offsets[node + 1] - s0;
    uint32 su = bin[(size_t)node * 8 + li];
    float ax = 0.f, ay = 0.f;
    int base = 0;
    for (; base + 16 <= deg; base += 16) {
        int i0 = csr[s0 + base + g];
        int i1 = csr[s0 + base + 8 + g];
        uint32 v0 = bin[(size_t)i0 * 8 + li];
        uint32 v1 = bin[(size_t)i1 * 8 + li];
        ax += bflo(v0); ay += bfhi(v0);
        ax += bflo(v1); ay += bfhi(v1);
    }
    for (; base < deg; base += 8) {
        int e = base + g;
        if (e < deg) {
            uint32 v = bin[(size_t)csr[s0 + e] * 8 + li];
            ax += bflo(v); ay += bfhi(v);
        }
    }
    ax += __shfl_xor(ax, 8, 64);  ay += __shfl_xor(ay, 8, 64);
    ax += __shfl_xor(ax, 16, 64); ay += __shfl_xor(ay, 16, 64);
    ax += __shfl_xor(ax, 32, 64); ay += __shfl_xor(ay, 32, 64);
    if (g == 0) {
        float inv = 1.f / fmaxf((float)deg, 1.f);
        uint32* bout = (uint32*)(xout + (size_t)s * N * 16);
        bout[(size_t)node * 8 + li] = pack2(bflo(su) + ax * inv, bfhi(su) + ay * inv);
    }
}

// C[M,128] = relu(A @ W + b) via mfma_f32_16x16x32_bf16; A and bf16 output in
// SLICED layout [slice][M][16]. Wave = 16 rows x 128 cols, block = 4 waves.
__global__ __launch_bounds__(256)
void gemm_mfma_kernel(const ushort16* __restrict__ A, const ushort16* __restrict__ Wt,
                      const float* __restrict__ bias, int M,
                      ushort16* __restrict__ outB,
                      const float* __restrict__ Wp, const float* __restrict__ bp,
                      float* __restrict__ outP) {
    const int tid = threadIdx.x;
    const int lane = tid & 63;
    const int wave = tid >> 6;
    const int l15 = lane & 15;
    const int quad = lane >> 4;
    const int r0 = blockIdx.x * 64 + wave * 16;

    int arow = r0 + l15;
    if (arow >= M) arow = M - 1;
    short8 afr[4];
#pragma unroll
    for (int kt = 0; kt < 4; ++kt) {
        // channels kt*32+quad*8 .. +7 -> slice kt*2+(quad>>1), offset (quad&1)*8
        const ushort16* ap = A + ((size_t)(kt * 2 + (quad >> 1)) * M + arow) * 16
                               + (quad & 1) * 8;
        afr[kt] = ld_frag(ap);
    }

    f32x4 acc[8];
#pragma unroll
    for (int t = 0; t < 8; ++t) acc[t] = (f32x4){0.f, 0.f, 0.f, 0.f};

#pragma unroll
    for (int t = 0; t < 8; ++t) {
        const ushort16* bptr = Wt + (size_t)(16 * t + l15) * 128 + quad * 8;
        short8 b0 = ld_frag(bptr);
        short8 b1 = ld_frag(bptr + 32);
        short8 b2 = ld_frag(bptr + 64);
        short8 b3 = ld_frag(bptr + 96);
        acc[t] = __builtin_amdgcn_mfma_f32_16x16x32_bf16(afr[0], b0, acc[t], 0, 0, 0);
        acc[t] = __builtin_amdgcn_mfma_f32_16x16x32_bf16(afr[1], b1, acc[t], 0, 0, 0);
        acc[t] = __builtin_amdgcn_mfma_f32_16x16x32_bf16(afr[2], b2, acc[t], 0, 0, 0);
        acc[t] = __builtin_amdgcn_mfma_f32_16x16x32_bf16(afr[3], b3, acc[t], 0, 0, 0);
    }

    if (outP) {
        float p[4][5];
#pragma unroll
        for (int r = 0; r < 4; ++r)
#pragma unroll
            for (int j = 0; j < 5; ++j) p[r][j] = 0.f;
#pragma unroll
        for (int t = 0; t < 8; ++t) {
            float wpl[5];
#pragma unroll
            for (int j = 0; j < 5; ++j) wpl[j] = Wp[(16 * t + l15) * 5 + j];
            float bt = bias[16 * t + l15];
            float ov[4];
            ov[0] = fmaxf(acc[t].x + bt, 0.f);
            ov[1] = fmaxf(acc[t].y + bt, 0.f);
            ov[2] = fmaxf(acc[t].z + bt, 0.f);
            ov[3] = fmaxf(acc[t].w + bt, 0.f);
#pragma unroll
            for (int r = 0; r < 4; ++r)
#pragma unroll
                for (int j = 0; j < 5; ++j) p[r][j] += ov[r] * wpl[j];
        }
#pragma unroll
        for (int m = 1; m <= 8; m <<= 1)
#pragma unroll
            for (int r = 0; r < 4; ++r)
#pragma unroll
                for (int j = 0; j < 5; ++j) p[r][j] += __shfl_xor(p[r][j], m, 64);
        if (l15 == 0) {
#pragma unroll
            for (int r = 0; r < 4; ++r) {
                int row = r0 + quad * 4 + r;
                if (row < M) {
#pragma unroll
                    for (int j = 0; j < 5; ++j) outP[(size_t)row * 5 + j] = p[r][j] + bp[j];
                }
            }
        }
    } else {
#pragma unroll
        for (int t = 0; t < 8; ++t) {   // col-tile t == slice t
            float bt = bias[16 * t + l15];
            float ov[4];
            ov[0] = fmaxf(acc[t].x + bt, 0.f);
            ov[1] = fmaxf(acc[t].y + bt, 0.f);
            ov[2] = fmaxf(acc[t].z + bt, 0.f);
            ov[3] = fmaxf(acc[t].w + bt, 0.f);
#pragma unroll
            for (int r = 0; r < 4; ++r) {
                float nb = __shfl_xor(ov[r], 1, 64);
                int row = r0 + quad * 4 + r;
                if (((l15 & 1) == 0) && row < M) {
                    *(uint32*)(outB + ((size_t)t * M + row) * 16 + l15) = pack2(ov[r], nb);
                }
            }
        }
    }
}

extern "C" void kernel_launch(void* const* d_in, const int* in_sizes, int n_in,
                              void* d_out, int out_size, void* d_ws, size_t ws_size,
                              hipStream_t stream) {
    const float* x     = (const float*)d_in[0];
    const int*   edges = (const int*)d_in[1];
    const float* W1    = (const float*)d_in[2];
    const float* b1    = (const float*)d_in[3];
    const float* W2    = (const float*)d_in[4];
    const float* b2    = (const float*)d_in[5];
    const float* Wp    = (const float*)d_in[6];
    const float* bp    = (const float*)d_in[7];
    float* out = (float*)d_out;

    const int N = in_sizes[0] / 128;   // 100000
    const int E = in_sizes[1] / 2;     // 1600000
    const int* src = edges;
    const int* tgt = edges + E;

    const int B  = (N + 255) >> 8;        // buckets (391)
    const int C  = 2048;                  // edges per partition block
    const int G1 = (E + C - 1) / C;       // partition blocks (782)
    const int n64 = N * 2;                // 64-float cvt groups

    char* ws = (char*)d_ws;
    size_t off = 0;
    auto alloc = [&](size_t bytes) {
        char* p = ws + off;
        off = (off + bytes + 255) & ~(size_t)255;
        return p;
    };
    int*      offsets = (int*)alloc((size_t)(N + 1) * 4);
    int*      csr     = (int*)alloc((size_t)E * 4);
    ushort16* xbs     = (ushort16*)alloc((size_t)N * 128 * 2);   // sliced [8][N][16]
    ushort16* hb1s    = (ushort16*)alloc((size_t)N * 128 * 2);   // sliced
    ushort16* combs   = (ushort16*)alloc((size_t)N * 128 * 2);   // sliced
    ushort16* Wt1     = (ushort16*)alloc(128 * 128 * 2);
    ushort16* Wt2     = (ushort16*)alloc(128 * 128 * 2);
    int*      hist    = (int*)alloc((size_t)G1 * B * 4);
    int*      total   = (int*)alloc((size_t)B * 4);
    uint32*   ebuf    = (uint32*)combs;  // alias: dead before agg writes combs
    (void)ws_size;

    hist_cvt_prep_kernel<<<G1 + 2, 256, 0, stream>>>(tgt, hist, x, (uint4*)xbs,
                                                     W1, W2, Wt1, Wt2, E, C, B, G1, n64, N);
    colscan_kernel<<<B, 256, 0, stream>>>(hist, total, G1, B);
    partition_kernel<<<G1, 256, 0, stream>>>(src, tgt, hist, total, ebuf, E, C, B);
    csr_kernel<<<B, 256, 0, stream>>>(ebuf, total, offsets, csr, N, B, E);

    const int aggBlocks  = ((N + 7) / 8) * 8;   // 8 slices x node-octets
    const int gemmBlocks = (N + 63) / 64;

    // layer 1: agg(xbs) -> combs; GEMM(W1) -> hb1s (sliced bf16)
    agg_sliced_kernel<<<aggBlocks, 512, 0, stream>>>(xbs, offsets, csr, combs, N);
    gemm_mfma_kernel<<<gemmBlocks, 256, 0, stream>>>(combs, Wt1, b1, N, hb1s,
                                                     nullptr, nullptr, nullptr);
    // layer 2: agg(hb1s) -> combs; GEMM(W2) + projection -> out
    agg_sliced_kernel<<<aggBlocks, 512, 0, stream>>>(hb1s, offsets, csr, combs, N);
    gemm_mfma_kernel<<<gemmBlocks, 256, 0, stream>>>(combs, Wt2, b2, N, nullptr,
                                                     Wp, bp, out);
}

// Round 11
// 359.804 us; speedup vs baseline: 1.7106x; 1.7106x over previous
//
#include <hip/hip_runtime.h>

typedef unsigned int uint32;
typedef unsigned short ushort16;

typedef __attribute__((ext_vector_type(8))) short short8;
typedef __attribute__((ext_vector_type(4))) float f32x4;

#define BMAX 512   // max buckets (N <= 130816)

// ---------------------------------------------------------------------------
// GNN: h1 = relu((x + mean_agg(x)) @ W1 + b1)
//      h2 = relu((h1 + mean_agg(h1)) @ W2 + b2)
//      out = h2 @ Wp + bp
// R11: revert R10 slicing (L2-localization worked — FETCH 188->41MB — but
//      4B/lane loads quartered payload/inst; R9's 1KB/inst full-row gather
//      at the 3.45TB/s L2-miss ceiling is the better operating point).
//      Build micro-opts: C=4096 (halve G1/hist/colscan), int4 edge reads,
//      uint4 ebuf reads.
// ---------------------------------------------------------------------------

__device__ __forceinline__ ushort16 f2bf(float f) {
    uint32 u = __float_as_uint(f);
    u += 0x7fffu + ((u >> 16) & 1u);       // round-to-nearest-even
    return (ushort16)(u >> 16);
}
__device__ __forceinline__ float bfhi(uint32 u) { return __uint_as_float(u & 0xffff0000u); }
__device__ __forceinline__ float bflo(uint32 u) { return __uint_as_float(u << 16); }
__device__ __forceinline__ uint32 pack2(float a, float b) {
    return (uint32)f2bf(a) | ((uint32)f2bf(b) << 16);
}

union U16 { uint4 u; short8 s; };
__device__ __forceinline__ short8 ld_frag(const ushort16* p) {
    U16 x; x.u = *(const uint4*)p; return x.s;
}

#define ACC8(v) \
    acc[0] += bflo(v.x); acc[1] += bfhi(v.x); \
    acc[2] += bflo(v.y); acc[3] += bfhi(v.y); \
    acc[4] += bflo(v.z); acc[5] += bfhi(v.z); \
    acc[6] += bflo(v.w); acc[7] += bfhi(v.w);

// exclusive scan of total[0..B) into bs[0..511] using 256 threads.
__device__ __forceinline__ void bucket_scan(const int* __restrict__ total, int B,
                                            int* bs /*[512]*/, int* sd /*[256]*/) {
    int tid = threadIdx.x;
    int v0 = (2 * tid     < B) ? total[2 * tid]     : 0;
    int v1 = (2 * tid + 1 < B) ? total[2 * tid + 1] : 0;
    int s = v0 + v1;
    sd[tid] = s;
    __syncthreads();
    for (int o = 1; o < 256; o <<= 1) {
        int t = (tid >= o) ? sd[tid - o] : 0;
        __syncthreads();
        sd[tid] += t;
        __syncthreads();
    }
    int excl = sd[tid] - s;
    bs[2 * tid]     = excl;
    bs[2 * tid + 1] = excl + v0;
    __syncthreads();
}

// A: per-chunk bucket histogram (int4 edge reads) + x->bf16 cvt;
// blocks >= G1 do Wt prep. Requires E % 4 == 0 (padded loop handles tail).
__global__ __launch_bounds__(256)
void hist_cvt_prep_kernel(const int* __restrict__ tgt, int* __restrict__ hist,
                          const float* __restrict__ x, uint4* __restrict__ xb,
                          const float* __restrict__ W1, const float* __restrict__ W2,
                          ushort16* __restrict__ Wt1, ushort16* __restrict__ Wt2,
                          int E, int C, int B, int G1, int n64) {
    int tid = threadIdx.x, blk = blockIdx.x;
    if (blk >= G1) {   // Wt prep blocks
        const float* W = (blk - G1) ? W2 : W1;
        ushort16* Wt = (blk - G1) ? Wt2 : Wt1;
        for (int i = tid; i < 16384; i += 256) {
            int k = i >> 7, c = i & 127;
            Wt[c * 128 + k] = f2bf(W[i]);
        }
        return;
    }
    __shared__ int lh[BMAX];
    for (int b = tid; b < B; b += 256) lh[b] = 0;
    __syncthreads();
    int q0 = blk * (C / 4), q1 = min(q0 + C / 4, E / 4);
    for (int q = q0 + tid; q < q1; q += 256) {
        int4 t = ((const int4*)tgt)[q];
        atomicAdd(&lh[t.x >> 8], 1);
        atomicAdd(&lh[t.y >> 8], 1);
        atomicAdd(&lh[t.z >> 8], 1);
        atomicAdd(&lh[t.w >> 8], 1);
    }
    if (blk == 0 && tid == 0) {
        for (int e = (E / 4) * 4; e < E; ++e) atomicAdd(&lh[tgt[e] >> 8], 1);
    }
    // cvt: grid-stride over 64-float groups (independent; hides under atomics)
    for (int i = blk * 256 + tid; i < n64; i += G1 * 256) {
        const float4* p = (const float4*)x + (size_t)i * 16;
        uint4* q = xb + (size_t)i * 8;
#pragma unroll
        for (int j = 0; j < 8; ++j) {
            float4 a = p[2 * j], bb = p[2 * j + 1];
            uint4 o;
            o.x = pack2(a.x, a.y); o.y = pack2(a.z, a.w);
            o.z = pack2(bb.x, bb.y); o.w = pack2(bb.z, bb.w);
            q[j] = o;
        }
    }
    __syncthreads();
    for (int b = tid; b < B; b += 256) hist[blk * B + b] = lh[b];
}

// B: for each bucket b, exclusive scan of hist[g][b] over g; total[b] = sum
__global__ __launch_bounds__(256)
void colscan_kernel(int* __restrict__ hist, int* __restrict__ total, int G1, int B) {
    __shared__ int sd[256];
    __shared__ int carrySh;
    int b = blockIdx.x, tid = threadIdx.x;
    if (tid == 0) carrySh = 0;
    __syncthreads();
    for (int g0 = 0; g0 < G1; g0 += 256) {
        int g = g0 + tid;
        int v = (g < G1) ? hist[g * B + b] : 0;
        int c0 = carrySh;
        sd[tid] = v;
        __syncthreads();
        for (int o = 1; o < 256; o <<= 1) {
            int t = (tid >= o) ? sd[tid - o] : 0;
            __syncthreads();
            sd[tid] += t;
            __syncthreads();
        }
        if (g < G1) hist[g * B + b] = sd[tid] - v + c0;
        int tot = sd[255];
        __syncthreads();
        if (tid == 0) carrySh = c0 + tot;
        __syncthreads();
    }
    if (tid == 0) total[b] = carrySh;
}

// D: scatter edges into bucket order (int4 reads); packed uint32.
__global__ __launch_bounds__(256)
void partition_kernel(const int* __restrict__ src, const int* __restrict__ tgt,
                      const int* __restrict__ hist, const int* __restrict__ total,
                      uint32* __restrict__ ebuf, int E, int C, int B) {
    __shared__ int bs[512];
    __shared__ int sd[256];
    __shared__ int cur[BMAX];
    int tid = threadIdx.x, blk = blockIdx.x;
    bucket_scan(total, B, bs, sd);
    for (int b = tid; b < B; b += 256) cur[b] = hist[blk * B + b] + bs[b];
    __syncthreads();
    int q0 = blk * (C / 4), q1 = min(q0 + C / 4, E / 4);
    for (int q = q0 + tid; q < q1; q += 256) {
        int4 t = ((const int4*)tgt)[q];
        int4 s = ((const int4*)src)[q];
        int p0 = atomicAdd(&cur[t.x >> 8], 1);
        int p1 = atomicAdd(&cur[t.y >> 8], 1);
        int p2 = atomicAdd(&cur[t.z >> 8], 1);
        int p3 = atomicAdd(&cur[t.w >> 8], 1);
        ebuf[p0] = ((uint32)(t.x & 255) << 24) | (uint32)s.x;
        ebuf[p1] = ((uint32)(t.y & 255) << 24) | (uint32)s.y;
        ebuf[p2] = ((uint32)(t.z & 255) << 24) | (uint32)s.z;
        ebuf[p3] = ((uint32)(t.w & 255) << 24) | (uint32)s.w;
    }
    if (blk == 0 && tid == 0) {
        for (int e = (E / 4) * 4; e < E; ++e) {
            int t = tgt[e], s = src[e];
            int p = atomicAdd(&cur[t >> 8], 1);
            ebuf[p] = ((uint32)(t & 255) << 24) | (uint32)s;
        }
    }
}

// E: per-bucket local count (uint4 reads) + scan -> offsets; cursor scatter.
__global__ __launch_bounds__(256)
void csr_kernel(const uint32* __restrict__ ebuf, const int* __restrict__ total,
                int* __restrict__ offsets, int* __restrict__ csr, int N, int B, int E) {
    __shared__ int bs[512];
    __shared__ int sd[256];
    __shared__ int cnt[256];
    int b = blockIdx.x, tid = threadIdx.x;
    bucket_scan(total, B, bs, sd);
    int s = bs[b];
    int n = bs[b + 1] - s;
    int t0 = b << 8;
    cnt[tid] = 0;
    __syncthreads();
    // count pass: uint4 over aligned interior, scalar edges at boundaries
    {
        int a0 = (s + 3) & ~3, a1 = (s + n) & ~3;   // aligned subrange
        for (int i = s + tid; i < min(a0, s + n); i += 256) atomicAdd(&cnt[ebuf[i] >> 24], 1);
        for (int q = a0 / 4 + tid; q < a1 / 4; q += 256) {
            uint4 e4 = ((const uint4*)ebuf)[q];
            atomicAdd(&cnt[e4.x >> 24], 1);
            atomicAdd(&cnt[e4.y >> 24], 1);
            atomicAdd(&cnt[e4.z >> 24], 1);
            atomicAdd(&cnt[e4.w >> 24], 1);
        }
        for (int i = max(a1, s) + tid; i < s + n; i += 256) atomicAdd(&cnt[ebuf[i] >> 24], 1);
    }
    __syncthreads();
    int v = cnt[tid];
    sd[tid] = v;
    __syncthreads();
    for (int o = 1; o < 256; o <<= 1) {
        int t = (tid >= o) ? sd[tid - o] : 0;
        __syncthreads();
        sd[tid] += t;
        __syncthreads();
    }
    int excl = sd[tid] - v;
    int t = t0 + tid;
    if (t < N) offsets[t] = s + excl;
    if (b == B - 1 && tid == 255) offsets[N] = E;
    __syncthreads();
    cnt[tid] = s + excl;   // cursor
    __syncthreads();
    for (int i = tid; i < n; i += 256) {
        uint32 e = ebuf[s + i];
        int slot = atomicAdd(&cnt[e >> 24], 1);
        csr[slot] = (int)(e & 0x00FFFFFFu);
    }
}

// one wave per node; 8 edges in flight; bf16 in, bf16 out (combined).
__global__ __launch_bounds__(256, 4)
void agg_combine_bf16_kernel(const ushort16* __restrict__ hb,
                             const int* __restrict__ offsets, const int* __restrict__ csr,
                             uint32* __restrict__ outb, int N) {
    int wid = (blockIdx.x * 256 + threadIdx.x) >> 6;
    int lane = threadIdx.x & 63;
    if (wid >= N) return;
    int g = lane >> 4, sl = lane & 15;
    int s0 = offsets[wid];
    int deg = offsets[wid + 1] - s0;
    int fi = sl * 4 + g;
    uint32 su = ((const uint32*)hb)[(size_t)wid * 64 + fi];

    float acc[8];
#pragma unroll
    for (int j = 0; j < 8; ++j) acc[j] = 0.f;

    int base = 0;
    for (; base + 8 <= deg; base += 8) {
        int i0 = csr[s0 + base + g];
        int i1 = csr[s0 + base + 4 + g];
        uint4 v0 = *(const uint4*)(hb + (size_t)i0 * 128 + sl * 8);
        uint4 v1 = *(const uint4*)(hb + (size_t)i1 * 128 + sl * 8);
        ACC8(v0); ACC8(v1);
    }
    for (; base < deg; base += 4) {
        int e = base + g;
        if (e < deg) {
            int s = csr[s0 + e];
            uint4 v = *(const uint4*)(hb + (size_t)s * 128 + sl * 8);
            ACC8(v);
        }
    }
#pragma unroll
    for (int j = 0; j < 8; ++j) {
        acc[j] += __shfl_xor(acc[j], 16, 64);
        acc[j] += __shfl_xor(acc[j], 32, 64);
    }
    float inv = 1.f / fmaxf((float)deg, 1.f);
    float ax = (g == 0) ? acc[0] : (g == 1) ? acc[2] : (g == 2) ? acc[4] : acc[6];
    float ay = (g == 0) ? acc[1] : (g == 1) ? acc[3] : (g == 2) ? acc[5] : acc[7];
    outb[(size_t)wid * 64 + fi] = pack2(bflo(su) + ax * inv, bfhi(su) + ay * inv);
}

// C[M,128] = relu(A[M,128] @ W + b) via mfma_f32_16x16x32_bf16.
// A bf16 row-major; Wt = W^T bf16 (Wt[c][k]). Wave = 16 rows x 128 cols,
// block = 4 waves = 64 rows. No LDS, no barriers.
__global__ __launch_bounds__(256)
void gemm_mfma_kernel(const ushort16* __restrict__ A, const ushort16* __restrict__ Wt,
                      const float* __restrict__ bias, int M,
                      ushort16* __restrict__ outB,
                      const float* __restrict__ Wp, const float* __restrict__ bp,
                      float* __restrict__ outP) {
    const int tid = threadIdx.x;
    const int lane = tid & 63;
    const int wave = tid >> 6;
    const int l15 = lane & 15;
    const int quad = lane >> 4;
    const int r0 = blockIdx.x * 64 + wave * 16;

    int arow = r0 + l15;
    if (arow >= M) arow = M - 1;
    const ushort16* aptr = A + (size_t)arow * 128 + quad * 8;
    short8 afr[4];
#pragma unroll
    for (int kt = 0; kt < 4; ++kt) afr[kt] = ld_frag(aptr + kt * 32);

    f32x4 acc[8];
#pragma unroll
    for (int t = 0; t < 8; ++t) acc[t] = (f32x4){0.f, 0.f, 0.f, 0.f};

#pragma unroll
    for (int t = 0; t < 8; ++t) {
        const ushort16* bptr = Wt + (size_t)(16 * t + l15) * 128 + quad * 8;
        short8 b0 = ld_frag(bptr);
        short8 b1 = ld_frag(bptr + 32);
        short8 b2 = ld_frag(bptr + 64);
        short8 b3 = ld_frag(bptr + 96);
        acc[t] = __builtin_amdgcn_mfma_f32_16x16x32_bf16(afr[0], b0, acc[t], 0, 0, 0);
        acc[t] = __builtin_amdgcn_mfma_f32_16x16x32_bf16(afr[1], b1, acc[t], 0, 0, 0);
        acc[t] = __builtin_amdgcn_mfma_f32_16x16x32_bf16(afr[2], b2, acc[t], 0, 0, 0);
        acc[t] = __builtin_amdgcn_mfma_f32_16x16x32_bf16(afr[3], b3, acc[t], 0, 0, 0);
    }

    if (outP) {
        float p[4][5];
#pragma unroll
        for (int r = 0; r < 4; ++r)
#pragma unroll
            for (int j = 0; j < 5; ++j) p[r][j] = 0.f;
#pragma unroll
        for (int t = 0; t < 8; ++t) {
            float wpl[5];
#pragma unroll
            for (int j = 0; j < 5; ++j) wpl[j] = Wp[(16 * t + l15) * 5 + j];
            float bt = bias[16 * t + l15];
            float ov[4];
            ov[0] = fmaxf(acc[t].x + bt, 0.f);
            ov[1] = fmaxf(acc[t].y + bt, 0.f);
            ov[2] = fmaxf(acc[t].z + bt, 0.f);
            ov[3] = fmaxf(acc[t].w + bt, 0.f);
#pragma unroll
            for (int r = 0; r < 4; ++r)
#pragma unroll
                for (int j = 0; j < 5; ++j) p[r][j] += ov[r] * wpl[j];
        }
#pragma unroll
        for (int m = 1; m <= 8; m <<= 1)
#pragma unroll
            for (int r = 0; r < 4; ++r)
#pragma unroll
                for (int j = 0; j < 5; ++j) p[r][j] += __shfl_xor(p[r][j], m, 64);
        if (l15 == 0) {
#pragma unroll
            for (int r = 0; r < 4; ++r) {
                int row = r0 + quad * 4 + r;
                if (row < M) {
#pragma unroll
                    for (int j = 0; j < 5; ++j) outP[(size_t)row * 5 + j] = p[r][j] + bp[j];
                }
            }
        }
    } else {
#pragma unroll
        for (int t = 0; t < 8; ++t) {
            float bt = bias[16 * t + l15];
            float ov[4];
            ov[0] = fmaxf(acc[t].x + bt, 0.f);
            ov[1] = fmaxf(acc[t].y + bt, 0.f);
            ov[2] = fmaxf(acc[t].z + bt, 0.f);
            ov[3] = fmaxf(acc[t].w + bt, 0.f);
#pragma unroll
            for (int r = 0; r < 4; ++r) {
                float nb = __shfl_xor(ov[r], 1, 64);
                int row = r0 + quad * 4 + r;
                if (((l15 & 1) == 0) && row < M) {
                    *(uint32*)(outB + (size_t)row * 128 + 16 * t + l15) = pack2(ov[r], nb);
                }
            }
        }
    }
}

extern "C" void kernel_launch(void* const* d_in, const int* in_sizes, int n_in,
                              void* d_out, int out_size, void* d_ws, size_t ws_size,
                              hipStream_t stream) {
    const float* x     = (const float*)d_in[0];
    const int*   edges = (const int*)d_in[1];
    const float* W1    = (const float*)d_in[2];
    const float* b1    = (const float*)d_in[3];
    const float* W2    = (const float*)d_in[4];
    const float* b2    = (const float*)d_in[5];
    const float* Wp    = (const float*)d_in[6];
    const float* bp    = (const float*)d_in[7];
    float* out = (float*)d_out;

    const int N = in_sizes[0] / 128;   // 100000
    const int E = in_sizes[1] / 2;     // 1600000
    const int* src = edges;
    const int* tgt = edges + E;

    const int B  = (N + 255) >> 8;        // buckets (391)
    const int C  = 4096;                  // edges per partition block
    const int G1 = (E + C - 1) / C;       // partition blocks (391)
    const int n64 = N * 2;                // 64-float cvt groups

    char* ws = (char*)d_ws;
    size_t off = 0;
    auto alloc = [&](size_t bytes) {
        char* p = ws + off;
        off = (off + bytes + 255) & ~(size_t)255;
        return p;
    };
    int*      offsets = (int*)alloc((size_t)(N + 1) * 4);
    int*      csr     = (int*)alloc((size_t)E * 4);
    ushort16* xb      = (ushort16*)alloc((size_t)N * 128 * 2);
    ushort16* hb1     = (ushort16*)alloc((size_t)N * 128 * 2);
    ushort16* bufAb   = (ushort16*)alloc((size_t)N * 128 * 2);  // combined, bf16
    ushort16* Wt1     = (ushort16*)alloc(128 * 128 * 2);
    ushort16* Wt2     = (ushort16*)alloc(128 * 128 * 2);
    int*      hist    = (int*)alloc((size_t)G1 * B * 4);
    int*      total   = (int*)alloc((size_t)B * 4);
    uint32*   ebuf    = (uint32*)bufAb;  // alias: dead before agg writes bufAb
    (void)ws_size;

    hist_cvt_prep_kernel<<<G1 + 2, 256, 0, stream>>>(tgt, hist, x, (uint4*)xb,
                                                     W1, W2, Wt1, Wt2, E, C, B, G1, n64);
    colscan_kernel<<<B, 256, 0, stream>>>(hist, total, G1, B);
    partition_kernel<<<G1, 256, 0, stream>>>(src, tgt, hist, total, ebuf, E, C, B);
    csr_kernel<<<B, 256, 0, stream>>>(ebuf, total, offsets, csr, N, B, E);

    const int aggBlocks  = (N + 3) / 4;
    const int gemmBlocks = (N + 63) / 64;

    // layer 1: agg(xb) -> bufAb; GEMM(W1) -> hb1 (bf16)
    agg_combine_bf16_kernel<<<aggBlocks, 256, 0, stream>>>(xb, offsets, csr, (uint32*)bufAb, N);
    gemm_mfma_kernel<<<gemmBlocks, 256, 0, stream>>>(bufAb, Wt1, b1, N, hb1,
                                                     nullptr, nullptr, nullptr);
    // layer 2: agg(hb1) -> bufAb; GEMM(W2) + projection -> out
    agg_combine_bf16_kernel<<<aggBlocks, 256, 0, stream>>>(hb1, offsets, csr, (uint32*)bufAb, N);
    gemm_mfma_kernel<<<gemmBlocks, 256, 0, stream>>>(bufAb, Wt2, b2, N, nullptr,
                                                     Wp, bp, out);
}